// Round 7
// baseline (475.214 us; speedup 1.0000x reference)
//
#include <hip/hip_runtime.h>

// SSIM loss, fused. R7: R6's barrier-free wave-autonomous design with 2x wave
// parallelism. R6 post-mortem: all pipes <25% busy, occupancy 34% -> latency-
// chain bound at 4 waves/SIMD (4096 waves total). Changes:
//  (1) WSTRIP 8->4: 8192 waves = 8 waves/SIMD (HW max).
//  (2) __launch_bounds__(256,8) caps VGPR at 64 so 8 waves/SIMD materialize.
//  (3) row loop fully unrolled -> compiler can hoist next-iter global loads
//      above current-iter window math (implicit software pipelining).
// Price: vertical warm-up overhead rises (11 warm rows per 4 output rows).

#define IMG_H 512
#define IMG_W 512
#define N_IMG 64
#define WSTRIP 4            // rows per wave
#define WAVES_PER_BLOCK 4
#define NTHREADS (64 * WAVES_PER_BLOCK)

__global__ __launch_bounds__(NTHREADS, 8) void ssim_kernel(const float* __restrict__ img1,
                                                           const float* __restrict__ img2,
                                                           float* __restrict__ ws) {
    const int t = threadIdx.x;
    const int lane = t & 63;
    const int w = t >> 6;
    const int b = blockIdx.y;
    const int r0 = (blockIdx.x * WAVES_PER_BLOCK + w) * WSTRIP;
    const float* __restrict__ p1 = img1 + (size_t)b * (IMG_H * IMG_W);
    const float* __restrict__ p2 = img2 + (size_t)b * (IMG_H * IMG_W);
    const int c0 = lane * 8;

    float Sx[8], Sy[8], Sxy[8], Sq[8];
#pragma unroll
    for (int j = 0; j < 8; ++j) { Sx[j] = 0.f; Sy[j] = 0.f; Sxy[j] = 0.f; Sq[j] = 0.f; }

    auto addrow = [&](int r) {
        const float* a = p1 + (size_t)r * IMG_W + c0;
        const float* bb = p2 + (size_t)r * IMG_W + c0;
        float4 xa = *(const float4*)a, xb = *(const float4*)(a + 4);
        float4 ya = *(const float4*)bb, yb = *(const float4*)(bb + 4);
        float xs[8] = {xa.x, xa.y, xa.z, xa.w, xb.x, xb.y, xb.z, xb.w};
        float ys[8] = {ya.x, ya.y, ya.z, ya.w, yb.x, yb.y, yb.z, yb.w};
#pragma unroll
        for (int j = 0; j < 8; ++j) {
            Sx[j] += xs[j];
            Sy[j] += ys[j];
            Sxy[j] = fmaf(xs[j], ys[j], Sxy[j]);
            Sq[j]  = fmaf(xs[j], xs[j], Sq[j]);
            Sq[j]  = fmaf(ys[j], ys[j], Sq[j]);
        }
    };
    auto subrow = [&](int r) {
        const float* a = p1 + (size_t)r * IMG_W + c0;
        const float* bb = p2 + (size_t)r * IMG_W + c0;
        float4 xa = *(const float4*)a, xb = *(const float4*)(a + 4);
        float4 ya = *(const float4*)bb, yb = *(const float4*)(bb + 4);
        float xs[8] = {xa.x, xa.y, xa.z, xa.w, xb.x, xb.y, xb.z, xb.w};
        float ys[8] = {ya.x, ya.y, ya.z, ya.w, yb.x, yb.y, yb.z, yb.w};
#pragma unroll
        for (int j = 0; j < 8; ++j) {
            Sx[j] -= xs[j];
            Sy[j] -= ys[j];
            Sxy[j] = fmaf(-xs[j], ys[j], Sxy[j]);
            Sq[j]  = fmaf(-xs[j], xs[j], Sq[j]);
            Sq[j]  = fmaf(-ys[j], ys[j], Sq[j]);
        }
    };

    // Warm vertical window for output row r0 (zero pad outside image).
    {
        int rlo = r0 - 5; if (rlo < 0) rlo = 0;
        int rhi = r0 + 5; if (rhi > IMG_H - 1) rhi = IMG_H - 1;
        for (int r = rlo; r <= rhi; ++r) addrow(r);
    }

    const bool lane_lo = (lane == 0);
    const bool lane_hi = (lane == 63);

    // Horizontal: gather 5-left/5-right halo via shfl, slide 11-tap window.
    auto hwin = [&](const float (&S)[8], float (&Wo)[8]) {
        float l[5], r[5];
#pragma unroll
        for (int k = 0; k < 5; ++k) l[k] = __shfl_up(S[3 + k], 1, 64);
#pragma unroll
        for (int k = 0; k < 5; ++k) r[k] = __shfl_down(S[k], 1, 64);
#pragma unroll
        for (int k = 0; k < 5; ++k) {
            l[k] = lane_lo ? 0.f : l[k];
            r[k] = lane_hi ? 0.f : r[k];
        }
        float acc0 = ((l[0] + l[1]) + (l[2] + l[3])) +
                     ((l[4] + S[0]) + (S[1] + S[2])) +
                     ((S[3] + S[4]) + S[5]);
        Wo[0] = acc0;
        const float addv[7] = {S[6], S[7], r[0], r[1], r[2], r[3], r[4]};
        const float subv[7] = {l[0], l[1], l[2], l[3], l[4], S[0], S[1]};
        float wv = acc0;
#pragma unroll
        for (int k = 0; k < 7; ++k) { wv = (wv + addv[k]) - subv[k]; Wo[k + 1] = wv; }
    };

    constexpr float inv  = 1.0f / 121.0f;
    constexpr float inv2 = 2.0f / 121.0f;
    constexpr float C1c = 0.01f * 0.01f;
    constexpr float C2c = 0.03f * 0.03f;
    float acc = 0.0f;

#pragma unroll
    for (int rr = 0; rr < WSTRIP; ++rr) {
        const int r = r0 + rr;
        if (rr > 0) {
            int ri = r + 5, ro = r - 6;
            if (ri < IMG_H) addrow(ri);
            if (ro >= 0)    subrow(ro);
        }
        float Wx[8], Wy[8], Wxy[8], Wq[8];
        hwin(Sx, Wx); hwin(Sy, Wy); hwin(Sxy, Wxy); hwin(Sq, Wq);
#pragma unroll
        for (int k = 0; k < 8; ++k) {
            float mu1 = Wx[k] * inv, mu2 = Wy[k] * inv;
            float m12 = mu1 * mu2;
            float P = fmaf(mu1, mu1, mu2 * mu2);          // mu1^2 + mu2^2
            float m12_2 = m12 + m12;                       // 2*mu1*mu2
            float s2 = fmaf(Wxy[k], inv2, -m12_2);         // 2*sigma12
            float A = fmaf(Wq[k], inv, -P);                // sig1^2 + sig2^2
            float num = (m12_2 + C1c) * (s2 + C2c);
            float den = (P + C1c) * (A + C2c);
            acc += __fdividef(num, den);
        }
    }

    // Wave reduction -> one atomic per wave (8192 total, negligible).
#pragma unroll
    for (int off = 32; off > 0; off >>= 1) acc += __shfl_down(acc, off);
    if (lane == 0) atomicAdd(ws, acc);
}

__global__ void ssim_finalize(const float* __restrict__ ws, float* __restrict__ out) {
    constexpr float inv_n = 1.0f / (float)((size_t)N_IMG * IMG_H * IMG_W);
    out[0] = 1.0f - ws[0] * inv_n;
}

extern "C" void kernel_launch(void* const* d_in, const int* in_sizes, int n_in,
                              void* d_out, int out_size, void* d_ws, size_t ws_size,
                              hipStream_t stream) {
    const float* img1 = (const float*)d_in[0];
    const float* img2 = (const float*)d_in[1];
    float* out = (float*)d_out;
    float* ws = (float*)d_ws;

    hipMemsetAsync(ws, 0, sizeof(float), stream);

    dim3 grid(IMG_H / (WAVES_PER_BLOCK * WSTRIP), N_IMG);   // (32, 64) = 2048 blocks
    ssim_kernel<<<grid, NTHREADS, 0, stream>>>(img1, img2, ws);
    ssim_finalize<<<1, 1, 0, stream>>>(ws, out);
}

// Round 8
// 474.316 us; speedup vs baseline: 1.0019x; 1.0019x over previous
//
#include <hip/hip_runtime.h>

// SSIM loss, fused. R8: R6's barrier-free wave-autonomous design + explicit
// 1-deep prefetch to break the per-row load->roll->hwin dependency chain.
// R6 post-mortem: all pipes <25%, chain latency exposed every row.
// R7 post-mortem: launch_bounds(,8) -> VGPR=32 -> 710 MB spill traffic. Never
// cap below ~128 here; state needs ~115 VGPRs.
// Structure per row iteration: (1) issue next roll's add/sub row loads,
// (2) hwin + SSIM combine on current S (~250 cy, no dependence on the loads),
// (3) wait + roll S. Load->use distance = one full window-math section,
// x4 resident waves/SIMD covers L2/HBM latency.

#define IMG_H 512
#define IMG_W 512
#define N_IMG 64
#define WSTRIP 8            // rows per wave -> 4096 waves = 4/SIMD (grid-bound)
#define WAVES_PER_BLOCK 4
#define NTHREADS (64 * WAVES_PER_BLOCK)

__global__ __launch_bounds__(NTHREADS, 4) void ssim_kernel(const float* __restrict__ img1,
                                                           const float* __restrict__ img2,
                                                           float* __restrict__ ws) {
    const int t = threadIdx.x;
    const int lane = t & 63;
    const int w = t >> 6;
    const int b = blockIdx.y;
    const int r0 = (blockIdx.x * WAVES_PER_BLOCK + w) * WSTRIP;
    const float* __restrict__ p1 = img1 + (size_t)b * (IMG_H * IMG_W);
    const float* __restrict__ p2 = img2 + (size_t)b * (IMG_H * IMG_W);
    const int c0 = lane * 8;

    float Sx[8], Sy[8], Sxy[8], Sq[8];
#pragma unroll
    for (int j = 0; j < 8; ++j) { Sx[j] = 0.f; Sy[j] = 0.f; Sxy[j] = 0.f; Sq[j] = 0.f; }

    auto loadrow = [&](int r, float (&xs)[8], float (&ys)[8]) {
        const float* a = p1 + (size_t)r * IMG_W + c0;
        const float* bq = p2 + (size_t)r * IMG_W + c0;
        float4 xa = *(const float4*)a, xb = *(const float4*)(a + 4);
        float4 ya = *(const float4*)bq, yb = *(const float4*)(bq + 4);
        xs[0] = xa.x; xs[1] = xa.y; xs[2] = xa.z; xs[3] = xa.w;
        xs[4] = xb.x; xs[5] = xb.y; xs[6] = xb.z; xs[7] = xb.w;
        ys[0] = ya.x; ys[1] = ya.y; ys[2] = ya.z; ys[3] = ya.w;
        ys[4] = yb.x; ys[5] = yb.y; ys[6] = yb.z; ys[7] = yb.w;
    };
    auto rollA = [&](const float (&xs)[8], const float (&ys)[8]) {
#pragma unroll
        for (int j = 0; j < 8; ++j) {
            Sx[j] += xs[j];
            Sy[j] += ys[j];
            Sxy[j] = fmaf(xs[j], ys[j], Sxy[j]);
            Sq[j]  = fmaf(xs[j], xs[j], Sq[j]);
            Sq[j]  = fmaf(ys[j], ys[j], Sq[j]);
        }
    };
    auto rollS = [&](const float (&xs)[8], const float (&ys)[8]) {
#pragma unroll
        for (int j = 0; j < 8; ++j) {
            Sx[j] -= xs[j];
            Sy[j] -= ys[j];
            Sxy[j] = fmaf(-xs[j], ys[j], Sxy[j]);
            Sq[j]  = fmaf(-xs[j], xs[j], Sq[j]);
            Sq[j]  = fmaf(-ys[j], ys[j], Sq[j]);
        }
    };

    // Warm vertical window for output row r0 (zero pad outside image).
    {
        int rlo = r0 - 5; if (rlo < 0) rlo = 0;
        int rhi = r0 + 5; if (rhi > IMG_H - 1) rhi = IMG_H - 1;
        for (int r = rlo; r <= rhi; ++r) {
            float xs[8], ys[8];
            loadrow(r, xs, ys);
            rollA(xs, ys);
        }
    }

    const bool lane_lo = (lane == 0);
    const bool lane_hi = (lane == 63);

    // Horizontal: gather 5-left/5-right halo via shfl, slide 11-tap window.
    auto hwin = [&](const float (&S)[8], float (&Wo)[8]) {
        float l[5], r[5];
#pragma unroll
        for (int k = 0; k < 5; ++k) l[k] = __shfl_up(S[3 + k], 1, 64);
#pragma unroll
        for (int k = 0; k < 5; ++k) r[k] = __shfl_down(S[k], 1, 64);
#pragma unroll
        for (int k = 0; k < 5; ++k) {
            l[k] = lane_lo ? 0.f : l[k];
            r[k] = lane_hi ? 0.f : r[k];
        }
        float acc0 = ((l[0] + l[1]) + (l[2] + l[3])) +
                     ((l[4] + S[0]) + (S[1] + S[2])) +
                     ((S[3] + S[4]) + S[5]);
        Wo[0] = acc0;
        const float addv[7] = {S[6], S[7], r[0], r[1], r[2], r[3], r[4]};
        const float subv[7] = {l[0], l[1], l[2], l[3], l[4], S[0], S[1]};
        float wv = acc0;
#pragma unroll
        for (int k = 0; k < 7; ++k) { wv = (wv + addv[k]) - subv[k]; Wo[k + 1] = wv; }
    };

    constexpr float inv  = 1.0f / 121.0f;
    constexpr float inv2 = 2.0f / 121.0f;
    constexpr float C1c = 0.01f * 0.01f;
    constexpr float C2c = 0.03f * 0.03f;
    float acc = 0.0f;

#pragma unroll
    for (int rr = 0; rr < WSTRIP; ++rr) {
        const int r = r0 + rr;
        // (1) PREFETCH: rows needed by the roll at the END of this iteration.
        float nax[8], nay[8], nsx[8], nsy[8];
        const bool doA = (rr < WSTRIP - 1) && (r + 6 < IMG_H);
        const bool doS = (rr < WSTRIP - 1) && (r - 5 >= 0);
        if (doA) loadrow(r + 6, nax, nay);
        if (doS) loadrow(r - 5, nsx, nsy);

        // (2) Window math on current S — independent of the loads above.
        float Wx[8], Wy[8], Wxy[8], Wq[8];
        hwin(Sx, Wx); hwin(Sy, Wy); hwin(Sxy, Wxy); hwin(Sq, Wq);
#pragma unroll
        for (int k = 0; k < 8; ++k) {
            float mu1 = Wx[k] * inv, mu2 = Wy[k] * inv;
            float m12 = mu1 * mu2;
            float P = fmaf(mu1, mu1, mu2 * mu2);          // mu1^2 + mu2^2
            float m12_2 = m12 + m12;                       // 2*mu1*mu2
            float s2 = fmaf(Wxy[k], inv2, -m12_2);         // 2*sigma12
            float A = fmaf(Wq[k], inv, -P);                // sig1^2 + sig2^2
            float num = (m12_2 + C1c) * (s2 + C2c);
            float den = (P + C1c) * (A + C2c);
            acc += __fdividef(num, den);
        }

        // (3) Roll S for the next row using the prefetched data.
        if (doA) rollA(nax, nay);
        if (doS) rollS(nsx, nsy);
    }

    // Wave reduction -> one atomic per wave (4096 total, negligible).
#pragma unroll
    for (int off = 32; off > 0; off >>= 1) acc += __shfl_down(acc, off);
    if (lane == 0) atomicAdd(ws, acc);
}

__global__ void ssim_finalize(const float* __restrict__ ws, float* __restrict__ out) {
    constexpr float inv_n = 1.0f / (float)((size_t)N_IMG * IMG_H * IMG_W);
    out[0] = 1.0f - ws[0] * inv_n;
}

extern "C" void kernel_launch(void* const* d_in, const int* in_sizes, int n_in,
                              void* d_out, int out_size, void* d_ws, size_t ws_size,
                              hipStream_t stream) {
    const float* img1 = (const float*)d_in[0];
    const float* img2 = (const float*)d_in[1];
    float* out = (float*)d_out;
    float* ws = (float*)d_ws;

    hipMemsetAsync(ws, 0, sizeof(float), stream);

    dim3 grid(IMG_H / (WAVES_PER_BLOCK * WSTRIP), N_IMG);   // (16, 64) = 1024 blocks
    ssim_kernel<<<grid, NTHREADS, 0, stream>>>(img1, img2, ws);
    ssim_finalize<<<1, 1, 0, stream>>>(ws, out);
}

// Round 9
// 255.173 us; speedup vs baseline: 1.8623x; 1.8588x over previous
//
#include <hip/hip_runtime.h>

// SSIM loss, fused. R9: R6's barrier-free wave-autonomous design, EXACTLY,
// with one isolated change: WSTRIP 8->4 => 2048 blocks, 8192 waves = 8
// waves/SIMD (hw max), doubling latency-hiding wave parallelism.
// R6 post-mortem: VGPR=40/no spill/no conflicts but duty ~18% at 4 waves/SIMD
// -> per-row load-latency bound. R7/R8 post-mortem: full unroll and
// conditionally-initialized prefetch arrays both demote state to scratch
// (560-710 MB WRITE_SIZE) -- avoided entirely; row loop stays non-unrolled,
// all loads unconditional within the taken branch.

#define IMG_H 512
#define IMG_W 512
#define N_IMG 64
#define WSTRIP 4            // rows per wave -> (32,64) grid, 8 waves/SIMD
#define WAVES_PER_BLOCK 4
#define NTHREADS (64 * WAVES_PER_BLOCK)

__global__ __launch_bounds__(NTHREADS, 4) void ssim_kernel(const float* __restrict__ img1,
                                                           const float* __restrict__ img2,
                                                           float* __restrict__ ws) {
    const int t = threadIdx.x;
    const int lane = t & 63;
    const int w = t >> 6;
    const int b = blockIdx.y;
    const int r0 = (blockIdx.x * WAVES_PER_BLOCK + w) * WSTRIP;
    const float* __restrict__ p1 = img1 + (size_t)b * (IMG_H * IMG_W);
    const float* __restrict__ p2 = img2 + (size_t)b * (IMG_H * IMG_W);
    const int c0 = lane * 8;

    float Sx[8], Sy[8], Sxy[8], Sq[8];
#pragma unroll
    for (int j = 0; j < 8; ++j) { Sx[j] = 0.f; Sy[j] = 0.f; Sxy[j] = 0.f; Sq[j] = 0.f; }

    auto addrow = [&](int r) {
        const float* a = p1 + (size_t)r * IMG_W + c0;
        const float* bb = p2 + (size_t)r * IMG_W + c0;
        float4 xa = *(const float4*)a, xb = *(const float4*)(a + 4);
        float4 ya = *(const float4*)bb, yb = *(const float4*)(bb + 4);
        float xs[8] = {xa.x, xa.y, xa.z, xa.w, xb.x, xb.y, xb.z, xb.w};
        float ys[8] = {ya.x, ya.y, ya.z, ya.w, yb.x, yb.y, yb.z, yb.w};
#pragma unroll
        for (int j = 0; j < 8; ++j) {
            Sx[j] += xs[j];
            Sy[j] += ys[j];
            Sxy[j] = fmaf(xs[j], ys[j], Sxy[j]);
            Sq[j]  = fmaf(xs[j], xs[j], Sq[j]);
            Sq[j]  = fmaf(ys[j], ys[j], Sq[j]);
        }
    };
    auto subrow = [&](int r) {
        const float* a = p1 + (size_t)r * IMG_W + c0;
        const float* bb = p2 + (size_t)r * IMG_W + c0;
        float4 xa = *(const float4*)a, xb = *(const float4*)(a + 4);
        float4 ya = *(const float4*)bb, yb = *(const float4*)(bb + 4);
        float xs[8] = {xa.x, xa.y, xa.z, xa.w, xb.x, xb.y, xb.z, xb.w};
        float ys[8] = {ya.x, ya.y, ya.z, ya.w, yb.x, yb.y, yb.z, yb.w};
#pragma unroll
        for (int j = 0; j < 8; ++j) {
            Sx[j] -= xs[j];
            Sy[j] -= ys[j];
            Sxy[j] = fmaf(-xs[j], ys[j], Sxy[j]);
            Sq[j]  = fmaf(-xs[j], xs[j], Sq[j]);
            Sq[j]  = fmaf(-ys[j], ys[j], Sq[j]);
        }
    };

    // Warm vertical window for output row r0 (zero pad outside image).
    {
        int rlo = r0 - 5; if (rlo < 0) rlo = 0;
        int rhi = r0 + 5; if (rhi > IMG_H - 1) rhi = IMG_H - 1;
        for (int r = rlo; r <= rhi; ++r) addrow(r);
    }

    const bool lane_lo = (lane == 0);
    const bool lane_hi = (lane == 63);

    // Horizontal: gather 5-left/5-right halo via shfl, slide 11-tap window.
    auto hwin = [&](const float (&S)[8], float (&Wo)[8]) {
        float l[5], r[5];
#pragma unroll
        for (int k = 0; k < 5; ++k) l[k] = __shfl_up(S[3 + k], 1, 64);
#pragma unroll
        for (int k = 0; k < 5; ++k) r[k] = __shfl_down(S[k], 1, 64);
#pragma unroll
        for (int k = 0; k < 5; ++k) {
            l[k] = lane_lo ? 0.f : l[k];
            r[k] = lane_hi ? 0.f : r[k];
        }
        float acc0 = ((l[0] + l[1]) + (l[2] + l[3])) +
                     ((l[4] + S[0]) + (S[1] + S[2])) +
                     ((S[3] + S[4]) + S[5]);
        Wo[0] = acc0;
        const float addv[7] = {S[6], S[7], r[0], r[1], r[2], r[3], r[4]};
        const float subv[7] = {l[0], l[1], l[2], l[3], l[4], S[0], S[1]};
        float wv = acc0;
#pragma unroll
        for (int k = 0; k < 7; ++k) { wv = (wv + addv[k]) - subv[k]; Wo[k + 1] = wv; }
    };

    constexpr float inv  = 1.0f / 121.0f;
    constexpr float inv2 = 2.0f / 121.0f;
    constexpr float C1c = 0.01f * 0.01f;
    constexpr float C2c = 0.03f * 0.03f;
    float acc = 0.0f;

    for (int rr = 0; rr < WSTRIP; ++rr) {
        const int r = r0 + rr;
        if (rr > 0) {
            int ri = r + 5, ro = r - 6;
            if (ri < IMG_H) addrow(ri);
            if (ro >= 0)    subrow(ro);
        }
        float Wx[8], Wy[8], Wxy[8], Wq[8];
        hwin(Sx, Wx); hwin(Sy, Wy); hwin(Sxy, Wxy); hwin(Sq, Wq);
#pragma unroll
        for (int k = 0; k < 8; ++k) {
            float mu1 = Wx[k] * inv, mu2 = Wy[k] * inv;
            float m12 = mu1 * mu2;
            float P = fmaf(mu1, mu1, mu2 * mu2);          // mu1^2 + mu2^2
            float m12_2 = m12 + m12;                       // 2*mu1*mu2
            float s2 = fmaf(Wxy[k], inv2, -m12_2);         // 2*sigma12
            float A = fmaf(Wq[k], inv, -P);                // sig1^2 + sig2^2
            float num = (m12_2 + C1c) * (s2 + C2c);
            float den = (P + C1c) * (A + C2c);
            acc += __fdividef(num, den);
        }
    }

    // Wave reduction -> one atomic per wave (8192 total, negligible).
#pragma unroll
    for (int off = 32; off > 0; off >>= 1) acc += __shfl_down(acc, off);
    if (lane == 0) atomicAdd(ws, acc);
}

__global__ void ssim_finalize(const float* __restrict__ ws, float* __restrict__ out) {
    constexpr float inv_n = 1.0f / (float)((size_t)N_IMG * IMG_H * IMG_W);
    out[0] = 1.0f - ws[0] * inv_n;
}

extern "C" void kernel_launch(void* const* d_in, const int* in_sizes, int n_in,
                              void* d_out, int out_size, void* d_ws, size_t ws_size,
                              hipStream_t stream) {
    const float* img1 = (const float*)d_in[0];
    const float* img2 = (const float*)d_in[1];
    float* out = (float*)d_out;
    float* ws = (float*)d_ws;

    hipMemsetAsync(ws, 0, sizeof(float), stream);

    dim3 grid(IMG_H / (WAVES_PER_BLOCK * WSTRIP), N_IMG);   // (32, 64) = 2048 blocks
    ssim_kernel<<<grid, NTHREADS, 0, stream>>>(img1, img2, ws);
    ssim_finalize<<<1, 1, 0, stream>>>(ws, out);
}